// Round 1
// baseline (22134.457 us; speedup 1.0000x reference)
//
#include <hip/hip_runtime.h>
#include <stdint.h>

#define B_ 256
#define T_ 512
#define D_ 128
#define H_ 256

typedef __attribute__((ext_vector_type(8))) _Float16 half8;
typedef __attribute__((ext_vector_type(4))) float f32x4;

// ws layout
#define WS_CTR  0        // 16 ints (group barrier counters)
#define WS_PART 256      // 16*256 floats fc partials
#define WS_H0   65536    // [2][256][256] f16 layer0 h double buffer
#define WS_H1   327680   // [2][256][256] f16 layer1 h double buffer
// total 589824 bytes

__device__ __forceinline__ float fast_sig(float x) {
    return 1.0f / (1.0f + __expf(-x));
}
__device__ __forceinline__ float fast_tanh(float x) {
    float xc = fminf(fmaxf(x, -30.0f), 30.0f);
    float e = __expf(-2.0f * xc);
    return (1.0f - e) / (1.0f + e);
}

// 8 consecutive fp32 -> fp16x8 fragment
__device__ __forceinline__ half8 cvt8(const float* p) {
    const f32x4* q = (const f32x4*)p;
    f32x4 a = q[0], b = q[1];
    half8 r;
    r[0] = (_Float16)a[0]; r[1] = (_Float16)a[1];
    r[2] = (_Float16)a[2]; r[3] = (_Float16)a[3];
    r[4] = (_Float16)b[0]; r[5] = (_Float16)b[1];
    r[6] = (_Float16)b[2]; r[7] = (_Float16)b[3];
    return r;
}

__global__ void lstm_init(char* ws) {
    if (threadIdx.x < 16) ((int*)(ws + WS_CTR))[threadIdx.x] = 0;
}

// grid 256 wgs x 256 thr. wg = (batch group g = blk&15) x (hidden slice sl = blk>>4)
// wave w (0..3) = gate index (i,f,g,o). Weights pinned in VGPRs as MFMA B-frags.
// Pipelined: iteration u computes layer0 step u (u<T) and layer1 step u-1 (u>=1).
__global__ __launch_bounds__(256, 2) void lstm_main(
    const float* __restrict__ x, const int* __restrict__ mask,
    const float* __restrict__ Wih0, const float* __restrict__ Whh0,
    const float* __restrict__ bih0, const float* __restrict__ bhh0,
    const float* __restrict__ Wih1, const float* __restrict__ Whh1,
    const float* __restrict__ bih1, const float* __restrict__ bhh1,
    const float* __restrict__ fcw, char* __restrict__ ws)
{
    const int tid  = threadIdx.x;
    const int blk  = blockIdx.x;
    const int g    = blk & 15;    // batch group (same-XCD heuristic)
    const int sl   = blk >> 4;    // hidden slice
    const int b0   = g * 16;
    const int j0   = sl * 16;
    const int w    = tid >> 6;    // wave = gate
    const int lane = tid & 63;
    const int row  = lane & 15;   // MFMA m (A) / n (B) index
    const int quad = lane >> 4;
    const int kb   = quad * 8;    // k offset within 32-k tile

    int*      ctr      = (int*)(ws + WS_CTR);
    float*    partials = (float*)(ws + WS_PART);
    _Float16* h0buf    = (_Float16*)(ws + WS_H0);
    _Float16* h1buf    = (_Float16*)(ws + WS_H1);

    __shared__ float gbuf[2048];  // [layer][gate][bb][jj]

    // ---- pin weights in registers (f16 B-frags), n = gate row ----
    const int n = w * H_ + j0 + row;
    half8 wA[12], wB[16];
#pragma unroll
    for (int kt = 0; kt < 4; ++kt) wA[kt]     = cvt8(&Wih0[(size_t)n * D_ + kt * 32 + kb]);
#pragma unroll
    for (int kt = 0; kt < 8; ++kt) wA[4 + kt] = cvt8(&Whh0[(size_t)n * H_ + kt * 32 + kb]);
#pragma unroll
    for (int kt = 0; kt < 8; ++kt) wB[kt]     = cvt8(&Wih1[(size_t)n * H_ + kt * 32 + kb]);
#pragma unroll
    for (int kt = 0; kt < 8; ++kt) wB[8 + kt] = cvt8(&Whh1[(size_t)n * H_ + kt * 32 + kb]);
    const float biasA = bih0[n] + bhh0[n];
    const float biasB = bih1[n] + bhh1[n];

    // ---- per-thread elementwise identity ----
    const int bb    = tid >> 4;   // batch within group
    const int jj    = tid & 15;   // hidden within slice
    const int bglob = b0 + bb;

    // sequence length (sum of left-contiguous mask row)
    int len = 0;
    {
        const int* mrow = mask + (size_t)bglob * T_ + jj * 32;
#pragma unroll
        for (int q = 0; q < 32; ++q) len += mrow[q];
#pragma unroll
        for (int o = 1; o < 16; o <<= 1) len += __shfl_xor(len, o, 16);
    }

    float c0 = 0.f, c1 = 0.f, hsave = 0.f;

    for (int u = 0; u <= T_; ++u) {
        f32x4 acc0 = {0.f, 0.f, 0.f, 0.f};
        f32x4 acc1 = {0.f, 0.f, 0.f, 0.f};

        if (u < T_) {  // layer0 x-part
            const float* xp = x + ((size_t)(b0 + row) * T_ + u) * D_ + kb;
#pragma unroll
            for (int kt = 0; kt < 4; ++kt) {
                half8 a = cvt8(xp + kt * 32);
                acc0 = __builtin_amdgcn_mfma_f32_16x16x32_f16(a, wA[kt], acc0, 0, 0, 0);
            }
        }
        if (u >= 1) {
            // h0_{u-1}: recurrent input of layer0 AND feed input of layer1 (shared A-frags)
            const _Float16* h0p = h0buf + ((size_t)((u - 1) & 1) * B_ + (b0 + row)) * H_ + kb;
#pragma unroll
            for (int kt = 0; kt < 8; ++kt) {
                half8 a = *(const half8*)(h0p + kt * 32);
                if (u < T_) acc0 = __builtin_amdgcn_mfma_f32_16x16x32_f16(a, wA[4 + kt], acc0, 0, 0, 0);
                acc1 = __builtin_amdgcn_mfma_f32_16x16x32_f16(a, wB[kt], acc1, 0, 0, 0);
            }
            if (u >= 2) {  // h1_{u-2}
                const _Float16* h1p = h1buf + ((size_t)((u - 2) & 1) * B_ + (b0 + row)) * H_ + kb;
#pragma unroll
                for (int kt = 0; kt < 8; ++kt) {
                    half8 a = *(const half8*)(h1p + kt * 32);
                    acc1 = __builtin_amdgcn_mfma_f32_16x16x32_f16(a, wB[8 + kt], acc1, 0, 0, 0);
                }
            }
        }

        // gates -> LDS (+bias). D-frag: value r is [m=quad*4+r][n=row]
        if (u < T_) {
#pragma unroll
            for (int r = 0; r < 4; ++r)
                gbuf[w * 256 + (quad * 4 + r) * 16 + row] = acc0[r] + biasA;
        }
        if (u >= 1) {
#pragma unroll
            for (int r = 0; r < 4; ++r)
                gbuf[1024 + w * 256 + (quad * 4 + r) * 16 + row] = acc1[r] + biasB;
        }
        __syncthreads();

        // elementwise: thread (bb, jj)
        const int idx = bb * 16 + jj;
        if (u < T_) {
            float gi = fast_sig(gbuf[idx]);
            float gf = fast_sig(gbuf[256 + idx]);
            float gg = fast_tanh(gbuf[512 + idx]);
            float go = fast_sig(gbuf[768 + idx]);
            c0 = gf * c0 + gi * gg;
            float h0v = go * fast_tanh(c0);
            h0buf[((size_t)(u & 1) * B_ + bglob) * H_ + j0 + jj] = (_Float16)h0v;
        }
        if (u >= 1) {
            float gi = fast_sig(gbuf[1024 + idx]);
            float gf = fast_sig(gbuf[1024 + 256 + idx]);
            float gg = fast_tanh(gbuf[1024 + 512 + idx]);
            float go = fast_sig(gbuf[1024 + 768 + idx]);
            c1 = gf * c1 + gi * gg;
            float h1v = go * fast_tanh(c1);
            h1buf[((size_t)((u - 1) & 1) * B_ + bglob) * H_ + j0 + jj] = (_Float16)h1v;
            if (u == len) hsave = h1v;  // s = u-1 == len-1
        }

        // ---- 16-wg group barrier (device scope), one per iteration ----
        __syncthreads();
        __threadfence();
        if (tid == 0) {
            __hip_atomic_fetch_add(&ctr[g], 1, __ATOMIC_RELEASE, __HIP_MEMORY_SCOPE_AGENT);
            const int target = 16 * (u + 1);
            int guard = 0;
            while (__hip_atomic_load(&ctr[g], __ATOMIC_ACQUIRE, __HIP_MEMORY_SCOPE_AGENT) < target) {
                __builtin_amdgcn_s_sleep(1);
                if (++guard > 200000) break;  // bounded: fail loud (wrong result), never hang
            }
        }
        __syncthreads();
        __threadfence();
    }

    // fc partials: sum over this wg's 16 j's
    float part = hsave * fcw[j0 + jj];
#pragma unroll
    for (int o = 1; o < 16; o <<= 1) part += __shfl_xor(part, o, 16);
    if (jj == 0) partials[sl * B_ + bglob] = part;
}

__global__ void lstm_fc(const float* __restrict__ fcb, const char* __restrict__ ws,
                        float* __restrict__ out) {
    const int b = threadIdx.x;
    const float* partials = (const float*)(ws + WS_PART);
    float s = fcb[0];
#pragma unroll
    for (int sl = 0; sl < 16; ++sl) s += partials[sl * B_ + b];
    out[b] = s;
}

extern "C" void kernel_launch(void* const* d_in, const int* in_sizes, int n_in,
                              void* d_out, int out_size, void* d_ws, size_t ws_size,
                              hipStream_t stream) {
    const float* xx    = (const float*)d_in[0];
    const int*   mask  = (const int*)d_in[1];
    const float* Wih0  = (const float*)d_in[2];
    const float* Whh0  = (const float*)d_in[3];
    const float* bih0  = (const float*)d_in[4];
    const float* bhh0  = (const float*)d_in[5];
    const float* Wih1  = (const float*)d_in[6];
    const float* Whh1  = (const float*)d_in[7];
    const float* bih1  = (const float*)d_in[8];
    const float* bhh1  = (const float*)d_in[9];
    const float* fcw   = (const float*)d_in[10];
    const float* fcb   = (const float*)d_in[11];

    lstm_init<<<dim3(1), dim3(64), 0, stream>>>((char*)d_ws);
    lstm_main<<<dim3(256), dim3(256), 0, stream>>>(
        xx, mask, Wih0, Whh0, bih0, bhh0, Wih1, Whh1, bih1, bhh1, fcw, (char*)d_ws);
    lstm_fc<<<dim3(1), dim3(256), 0, stream>>>(fcb, (const char*)d_ws, (float*)d_out);
}

// Round 3
// 2545.100 us; speedup vs baseline: 8.6969x; 8.6969x over previous
//
#include <hip/hip_runtime.h>
#include <stdint.h>

#define B_ 256
#define T_ 512
#define D_ 128
#define H_ 256

typedef __attribute__((ext_vector_type(8))) _Float16 half8;
typedef __attribute__((ext_vector_type(4))) float f32x4;

// ws layout (bytes)
#define WS_CTR  0        // 16 counters, spaced 128 B apart (g*32 ints)
#define WS_PART 4096     // 16*256 floats fc partials
#define WS_H0   65536    // [2][256][256] f16 layer0 h double buffer
#define WS_H1   327680   // [2][256][256] f16 layer1 h double buffer

__device__ __forceinline__ float fast_sig(float x) {
    return 1.0f / (1.0f + __expf(-x));
}
__device__ __forceinline__ float fast_tanh(float x) {
    float xc = fminf(fmaxf(x, -30.0f), 30.0f);
    float e = __expf(-2.0f * xc);
    return (1.0f - e) / (1.0f + e);
}
__device__ __forceinline__ half8 cvt8(const float* p) {
    const f32x4* q = (const f32x4*)p;
    f32x4 a = q[0], b = q[1];
    half8 r;
    r[0] = (_Float16)a[0]; r[1] = (_Float16)a[1];
    r[2] = (_Float16)a[2]; r[3] = (_Float16)a[3];
    r[4] = (_Float16)b[0]; r[5] = (_Float16)b[1];
    r[6] = (_Float16)b[2]; r[7] = (_Float16)b[3];
    return r;
}

// ---- MALL-coherent primitives (single coherence point: sc0 sc1 = device) ----
// 8x dwordx4 loads from MALL, NO waitcnt (caller must wait before consuming).
__device__ __forceinline__ void load8_mall_nowait(const _Float16* p, half8* f) {
    asm volatile(
        "global_load_dwordx4 %0, %8, off sc0 sc1\n\t"
        "global_load_dwordx4 %1, %8, off offset:64 sc0 sc1\n\t"
        "global_load_dwordx4 %2, %8, off offset:128 sc0 sc1\n\t"
        "global_load_dwordx4 %3, %8, off offset:192 sc0 sc1\n\t"
        "global_load_dwordx4 %4, %8, off offset:256 sc0 sc1\n\t"
        "global_load_dwordx4 %5, %8, off offset:320 sc0 sc1\n\t"
        "global_load_dwordx4 %6, %8, off offset:384 sc0 sc1\n\t"
        "global_load_dwordx4 %7, %8, off offset:448 sc0 sc1"
        : "=&v"(f[0]), "=&v"(f[1]), "=&v"(f[2]), "=&v"(f[3]),
          "=&v"(f[4]), "=&v"(f[5]), "=&v"(f[6]), "=&v"(f[7])
        : "v"(p) : "memory");
}
// Same but ends with waitcnt(0): all outstanding loads (incl. a prior nowait
// block) are complete after this returns.
__device__ __forceinline__ void load8_mall_wait(const _Float16* p, half8* f) {
    asm volatile(
        "global_load_dwordx4 %0, %8, off sc0 sc1\n\t"
        "global_load_dwordx4 %1, %8, off offset:64 sc0 sc1\n\t"
        "global_load_dwordx4 %2, %8, off offset:128 sc0 sc1\n\t"
        "global_load_dwordx4 %3, %8, off offset:192 sc0 sc1\n\t"
        "global_load_dwordx4 %4, %8, off offset:256 sc0 sc1\n\t"
        "global_load_dwordx4 %5, %8, off offset:320 sc0 sc1\n\t"
        "global_load_dwordx4 %6, %8, off offset:384 sc0 sc1\n\t"
        "global_load_dwordx4 %7, %8, off offset:448 sc0 sc1\n\t"
        "s_waitcnt vmcnt(0)"
        : "=&v"(f[0]), "=&v"(f[1]), "=&v"(f[2]), "=&v"(f[3]),
          "=&v"(f[4]), "=&v"(f[5]), "=&v"(f[6]), "=&v"(f[7])
        : "v"(p) : "memory");
}
// fp16 write-through store to MALL.
__device__ __forceinline__ void store_h_mall(_Float16* p, float v) {
    union { _Float16 h; short s; } u;
    u.h = (_Float16)v;
    int vi = u.s;
    asm volatile("global_store_short %0, %1, off sc0 sc1" :: "v"(p), "v"(vi) : "memory");
}
// Device-scope counter ops (atomics execute at MALL by default — m20).
__device__ __forceinline__ void atomic_inc_mall(int* p) {
    int one = 1;
    asm volatile("global_atomic_add %0, %1, off\n\ts_waitcnt vmcnt(0)"
                 :: "v"(p), "v"(one) : "memory");
}
__device__ __forceinline__ int load_ctr_mall(const int* p) {
    int v;
    asm volatile("global_load_dword %0, %1, off sc0 sc1\n\ts_waitcnt vmcnt(0)"
                 : "=&v"(v) : "v"(p) : "memory");
    return v;
}

__global__ void lstm_init(char* ws) {
    if (threadIdx.x < 16) ((int*)ws)[threadIdx.x * 32] = 0;
    // kernel-end release flushes these to MALL before lstm_main starts
}

// grid 256 wgs x 256 thr. wg = (batch group g = blk&15) x (hidden slice sl = blk>>4)
// wave w = gate (i,f,g,o); weights pinned in regs as f16 MFMA B-frags.
// Layer-pipelined: iter u does layer0 step u (u<T) and layer1 step u-1 (u>=1).
// All cross-wg state (h buffers, counters) lives at MALL via sc0 sc1 ops —
// one coherence point, no fences, no placement assumptions (G16-safe).
__global__ __launch_bounds__(256, 2) void lstm_main(
    const float* __restrict__ x, const int* __restrict__ mask,
    const float* __restrict__ Wih0, const float* __restrict__ Whh0,
    const float* __restrict__ bih0, const float* __restrict__ bhh0,
    const float* __restrict__ Wih1, const float* __restrict__ Whh1,
    const float* __restrict__ bih1, const float* __restrict__ bhh1,
    const float* __restrict__ fcw, char* __restrict__ ws)
{
    const int tid  = threadIdx.x;
    const int blk  = blockIdx.x;
    const int g    = blk & 15;    // batch group
    const int sl   = blk >> 4;    // hidden slice
    const int b0   = g * 16;
    const int j0   = sl * 16;
    const int w    = tid >> 6;
    const int lane = tid & 63;
    const int row  = lane & 15;
    const int quad = lane >> 4;
    const int kb   = quad * 8;

    int*      ctr      = (int*)(ws + WS_CTR) + g * 32;
    float*    partials = (float*)(ws + WS_PART);
    _Float16* h0buf    = (_Float16*)(ws + WS_H0);
    _Float16* h1buf    = (_Float16*)(ws + WS_H1);

    __shared__ float gbuf[2048];

    // ---- pin weights in registers (f16 B-frags), n = gate row ----
    const int n = w * H_ + j0 + row;
    half8 wA[12], wB[16];
#pragma unroll
    for (int kt = 0; kt < 4; ++kt) wA[kt]     = cvt8(&Wih0[(size_t)n * D_ + kt * 32 + kb]);
#pragma unroll
    for (int kt = 0; kt < 8; ++kt) wA[4 + kt] = cvt8(&Whh0[(size_t)n * H_ + kt * 32 + kb]);
#pragma unroll
    for (int kt = 0; kt < 8; ++kt) wB[kt]     = cvt8(&Wih1[(size_t)n * H_ + kt * 32 + kb]);
#pragma unroll
    for (int kt = 0; kt < 8; ++kt) wB[8 + kt] = cvt8(&Whh1[(size_t)n * H_ + kt * 32 + kb]);
    const float biasA = bih0[n] + bhh0[n];
    const float biasB = bih1[n] + bhh1[n];

    const int bb    = tid >> 4;
    const int jj    = tid & 15;
    const int bglob = b0 + bb;

    int len = 0;
    {
        const int* mrow = mask + (size_t)bglob * T_ + jj * 32;
#pragma unroll
        for (int q = 0; q < 32; ++q) len += mrow[q];
#pragma unroll
        for (int o = 1; o < 16; o <<= 1) len += __shfl_xor(len, o, 16);
    }

    float c0 = 0.f, c1 = 0.f, hsave = 0.f;

    // x-part MFMAs for step 0 (prefetched; recomputed each iter pre-barrier)
    f32x4 xacc = {0.f, 0.f, 0.f, 0.f};
    {
        const float* xp = x + ((size_t)(b0 + row) * T_) * D_ + kb;
#pragma unroll
        for (int kt = 0; kt < 4; ++kt)
            xacc = __builtin_amdgcn_mfma_f32_16x16x32_f16(cvt8(xp + kt * 32), wA[kt], xacc, 0, 0, 0);
    }

    for (int u = 0; u <= T_; ++u) {
        f32x4 acc0 = xacc;                 // layer0 x-part (valid when u<T)
        f32x4 acc1 = {0.f, 0.f, 0.f, 0.f};

        if (u >= 1) {
            half8 hg[8];  // h1_{u-2} frags (issued first, waited by h0 block)
            if (u >= 2)
                load8_mall_nowait(h1buf + ((size_t)((u - 2) & 1) * B_ + (b0 + row)) * H_ + kb, hg);
            half8 hf[8];  // h0_{u-1} frags
            load8_mall_wait(h0buf + ((size_t)((u - 1) & 1) * B_ + (b0 + row)) * H_ + kb, hf);
            // acc1 chain goes through hf-MFMAs first, so hg consumers can't
            // be scheduled before the waitcnt above.
#pragma unroll
            for (int kt = 0; kt < 8; ++kt) {
                if (u < T_) acc0 = __builtin_amdgcn_mfma_f32_16x16x32_f16(hf[kt], wA[4 + kt], acc0, 0, 0, 0);
                acc1 = __builtin_amdgcn_mfma_f32_16x16x32_f16(hf[kt], wB[kt], acc1, 0, 0, 0);
            }
            if (u >= 2) {
#pragma unroll
                for (int kt = 0; kt < 8; ++kt)
                    acc1 = __builtin_amdgcn_mfma_f32_16x16x32_f16(hg[kt], wB[8 + kt], acc1, 0, 0, 0);
            }
        }

        // gates -> LDS (+bias). D-frag: value r is [m=quad*4+r][n=row]
        if (u < T_) {
#pragma unroll
            for (int r = 0; r < 4; ++r)
                gbuf[w * 256 + (quad * 4 + r) * 16 + row] = acc0[r] + biasA;
        }
        if (u >= 1) {
#pragma unroll
            for (int r = 0; r < 4; ++r)
                gbuf[1024 + w * 256 + (quad * 4 + r) * 16 + row] = acc1[r] + biasB;
        }
        __syncthreads();

        const int idx = bb * 16 + jj;
        if (u < T_) {
            float gi = fast_sig(gbuf[idx]);
            float gf = fast_sig(gbuf[256 + idx]);
            float gg = fast_tanh(gbuf[512 + idx]);
            float go = fast_sig(gbuf[768 + idx]);
            c0 = gf * c0 + gi * gg;
            float h0v = go * fast_tanh(c0);
            store_h_mall(&h0buf[((size_t)(u & 1) * B_ + bglob) * H_ + j0 + jj], h0v);
        }
        if (u >= 1) {
            float gi = fast_sig(gbuf[1024 + idx]);
            float gf = fast_sig(gbuf[1024 + 256 + idx]);
            float gg = fast_tanh(gbuf[1024 + 512 + idx]);
            float go = fast_sig(gbuf[1024 + 768 + idx]);
            c1 = gf * c1 + gi * gg;
            float h1v = go * fast_tanh(c1);
            store_h_mall(&h1buf[((size_t)((u - 1) & 1) * B_ + bglob) * H_ + j0 + jj], h1v);
            if (u == len) hsave = h1v;
        }

        // x-part MFMAs for step u+1 (off critical path; overlaps store-ack)
        xacc[0] = 0.f; xacc[1] = 0.f; xacc[2] = 0.f; xacc[3] = 0.f;
        if (u + 1 < T_) {
            const float* xp = x + ((size_t)(b0 + row) * T_ + (u + 1)) * D_ + kb;
#pragma unroll
            for (int kt = 0; kt < 4; ++kt)
                xacc = __builtin_amdgcn_mfma_f32_16x16x32_f16(cvt8(xp + kt * 32), wA[kt], xacc, 0, 0, 0);
        }

        // ---- 16-wg group barrier at MALL (one per step; none after last) ----
        if (u < T_) {
            asm volatile("s_waitcnt vmcnt(0)" ::: "memory");  // h stores at MALL
            __syncthreads();                                   // all waves drained
            if (tid == 0) {
                atomic_inc_mall(ctr);
                const int target = 16 * (u + 1);
                int guard = 0;
                while (load_ctr_mall(ctr) < target) {
                    if (++guard > (1 << 15)) break;  // bounded: fail loud, never hang
                }
            }
            __syncthreads();
        }
    }

    float part = hsave * fcw[j0 + jj];
#pragma unroll
    for (int o = 1; o < 16; o <<= 1) part += __shfl_xor(part, o, 16);
    if (jj == 0) partials[sl * B_ + bglob] = part;
}

__global__ void lstm_fc(const float* __restrict__ fcb, const char* __restrict__ ws,
                        float* __restrict__ out) {
    const int b = threadIdx.x;
    const float* partials = (const float*)(ws + WS_PART);
    float s = fcb[0];
#pragma unroll
    for (int sl = 0; sl < 16; ++sl) s += partials[sl * B_ + b];
    out[b] = s;
}

extern "C" void kernel_launch(void* const* d_in, const int* in_sizes, int n_in,
                              void* d_out, int out_size, void* d_ws, size_t ws_size,
                              hipStream_t stream) {
    const float* xx    = (const float*)d_in[0];
    const int*   mask  = (const int*)d_in[1];
    const float* Wih0  = (const float*)d_in[2];
    const float* Whh0  = (const float*)d_in[3];
    const float* bih0  = (const float*)d_in[4];
    const float* bhh0  = (const float*)d_in[5];
    const float* Wih1  = (const float*)d_in[6];
    const float* Whh1  = (const float*)d_in[7];
    const float* bih1  = (const float*)d_in[8];
    const float* bhh1  = (const float*)d_in[9];
    const float* fcw   = (const float*)d_in[10];
    const float* fcb   = (const float*)d_in[11];

    lstm_init<<<dim3(1), dim3(64), 0, stream>>>((char*)d_ws);
    lstm_main<<<dim3(256), dim3(256), 0, stream>>>(
        xx, mask, Wih0, Whh0, bih0, bhh0, Wih1, Whh1, bih1, bhh1, fcw, (char*)d_ws);
    lstm_fc<<<dim3(1), dim3(256), 0, stream>>>(fcb, (const char*)d_ws, (float*)d_out);
}